// Round 20
// baseline (204.408 us; speedup 1.0000x reference)
//
#include <hip/hip_runtime.h>
#include <hip/hip_fp16.h>

#define HEADS 4
#define HID 32
#define DCH 128            // HEADS*HID
#define OUTC 10
#define NSLOPE 0.2f

#define SCAN_T 256
#define SCAN_PT 8
#define SCAN_ELEMS (SCAN_T * SCAN_PT)   // 2048 per scan block

#define POOL_BLOCKS 2048
#define BN1 64             // nodes per conv1 block (512 threads)

// ================= CSR build (dst-major) =================
// deg pass records rank AND class packed in 16 bits -> scatter is atomic-free
// and needs no random x gather.
__global__ void k_deg(const int* __restrict__ esrc, const int* __restrict__ edst,
                      const int* __restrict__ x, int E, int N,
                      int* __restrict__ deg, unsigned short* __restrict__ rank) {
    int e = blockIdx.x * blockDim.x + threadIdx.x;
    int EP = E + N;
    if (e >= EP) return;
    int s, d;
    if (e < E) { s = esrc[e]; d = edst[e]; } else { s = e - E; d = s; }
    int r = atomicAdd(&deg[d], 1);
    rank[e] = (unsigned short)((r << 5) | x[s]);
}

__global__ void k_scan_a(const int* __restrict__ deg, int* __restrict__ rowstart,
                         int* __restrict__ bsum, int N) {
    __shared__ int sh[SCAN_T];
    int base = blockIdx.x * SCAN_ELEMS;
    int t = threadIdx.x;
    int v[SCAN_PT];
    int s = 0;
#pragma unroll
    for (int i = 0; i < SCAN_PT; i++) {
        int idx = base + t * SCAN_PT + i;
        int dv = (idx < N) ? deg[idx] : 0;
        s += dv; v[i] = s;
    }
    sh[t] = s;
    __syncthreads();
    for (int off = 1; off < SCAN_T; off <<= 1) {
        int add = (t >= off) ? sh[t - off] : 0;
        __syncthreads();
        sh[t] += add;
        __syncthreads();
    }
    int excl = (t > 0) ? sh[t - 1] : 0;
#pragma unroll
    for (int i = 0; i < SCAN_PT; i++) {
        int idx = base + t * SCAN_PT + i;
        if (idx < N) rowstart[idx + 1] = v[i] + excl;
    }
    if (t == SCAN_T - 1) bsum[blockIdx.x] = sh[t];
}

// ---- block 0: exclusive scan of bsum; block 1: build EXPT2/was3/wad3 tables
__global__ void k_scanb_tables(int* __restrict__ bsum, int nb,
        const float* __restrict__ W1, const float* __restrict__ as1, const float* __restrict__ ad1,
        const float* __restrict__ W3, const float* __restrict__ as3, const float* __restrict__ ad3,
        float* __restrict__ EXPT2, float* __restrict__ was3, float* __restrict__ wad3) {
    if (blockIdx.x == 0) {
        __shared__ int sh[1024];
        int t = threadIdx.x;
        sh[t] = (t < nb) ? bsum[t] : 0;
        __syncthreads();
        for (int off = 1; off < 1024; off <<= 1) {
            int add = (t >= off) ? sh[t - off] : 0;
            __syncthreads();
            sh[t] += add;
            __syncthreads();
        }
        if (t < nb) bsum[t] = (t > 0) ? sh[t - 1] : 0;
    } else {
        __shared__ float ts[32][HEADS], td[32][HEADS];
        int t = threadIdx.x;
        if (t < 128) {
            int cs = t >> 2, h = t & 3;
            const float* w = W1 + cs * DCH + h * HID;
            const float* a = as1 + h * HID;
            const float* b = ad1 + h * HID;
            float s1 = 0.f, s2 = 0.f;
#pragma unroll
            for (int j = 0; j < HID; j++) { float wv = w[j]; s1 = fmaf(wv, a[j], s1); s2 = fmaf(wv, b[j], s2); }
            ts[cs][h] = s1; td[cs][h] = s2;
        }
        __syncthreads();
        if (t < 128) {
            int h = t >> 5, cs = t & 31;
            for (int cd = 0; cd < 32; cd++) {
                float ev = ts[cs][h] + td[cd][h];
                ev = ev >= 0.f ? ev : NSLOPE * ev;
                EXPT2[cd * DCH + t] = __expf(ev);
            }
            for (int hh = 0; hh < HEADS; hh++) {
                const float* wr = W3 + (size_t)t * DCH + hh * HID;
                const float* a = as3 + hh * HID;
                const float* b = ad3 + hh * HID;
                float s1 = 0.f, s2 = 0.f;
#pragma unroll
                for (int j = 0; j < HID; j++) { float wv = wr[j]; s1 = fmaf(wv, a[j], s1); s2 = fmaf(wv, b[j], s2); }
                was3[hh * DCH + t] = s1; wad3[hh * DCH + t] = s2;
            }
        }
    }
}

// ---- scan finish + graph bounds + pool zero (merged elementwise pass)
__global__ void k_scan_c_bounds(int* __restrict__ rowstart, const int* __restrict__ boff,
                                const int* __restrict__ batch, int* __restrict__ gstart,
                                float* __restrict__ pool, int N, int G) {
    int i = blockIdx.x * blockDim.x + threadIdx.x;
    if (i < G * DCH) pool[i] = 0.f;
    if (i < N) {
        rowstart[i + 1] += boff[i / SCAN_ELEMS];
        if (i == 0) rowstart[0] = 0;
    }
    if (i > N) return;
    if (i == 0) {
        int b0 = batch[0];
        for (int g = 0; g <= b0; g++) gstart[g] = 0;
    } else if (i == N) {
        int bl = batch[N - 1];
        for (int g = bl + 1; g <= G; g++) gstart[g] = N;
    } else {
        int b = batch[i], bp = batch[i - 1];
        for (int g = bp + 1; g <= b; g++) gstart[g] = i;
    }
}

// ---- single-pass scatter, atomic-free via packed rank16.
__global__ void k_scatter1p(const int* __restrict__ esrc, const int* __restrict__ edst,
                            int E, int N, const int* __restrict__ rowstart,
                            const unsigned short* __restrict__ rank,
                            int* __restrict__ csr) {
    int e = blockIdx.x * blockDim.x + threadIdx.x;
    int EP = E + N;
    if (e >= EP) return;
    int s, d;
    if (e < E) { s = esrc[e]; d = edst[e]; } else { s = e - E; d = s; }
    unsigned short rk = rank[e];
    int pos = rowstart[d] + (rk >> 5);
    csr[pos] = (s << 5) | (rk & 31);
}

// ================= conv1: padded-LDS histogram + GEMM + fused conv3 logits ========
__global__ __launch_bounds__(512) void k_conv1b(
        const int* __restrict__ rowstart, const int* __restrict__ csr,
        const int* __restrict__ x, const float* __restrict__ W1,
        const float* __restrict__ EXPT2, const float* __restrict__ b1,
        const float* __restrict__ was3, const float* __restrict__ wad3,
        __half* __restrict__ h1, float* __restrict__ asrc, float* __restrict__ adst,
        int N) {
    __shared__ float El[32 * 132 + 1];      // EXPT2 padded [cd*132 + h*33 + k]
    __shared__ int   hist[BN1][33];
    __shared__ int   xdl[BN1];
    int t = threadIdx.x;
    int r0 = blockIdx.x * BN1;
    for (int i = t; i < 32 * DCH; i += 512) {
        int cd = i >> 7, rem = i & 127;
        int hh = rem >> 5, kk = rem & 31;
        El[cd * 132 + hh * 33 + kk] = EXPT2[i];
    }
    for (int i = t; i < BN1 * 33; i += 512) ((int*)hist)[i] = 0;
    if (t < BN1) {
        int node = r0 + t;
        xdl[t] = (node < N) ? x[node] : 0;
    }
    __syncthreads();
    {   // 8 threads per node build its class histogram (streaming csr reads)
        int ln = t >> 3, sub = t & 7;
        int node = r0 + ln;
        if (node < N) {
            int p0 = rowstart[node], p1 = rowstart[node + 1];
            for (int p = p0 + sub; p < p1; p += 8)
                atomicAdd(&hist[ln][csr[p] & 31], 1);
        }
    }
    __syncthreads();
    int ct = t & 31, rt = t >> 5;           // rt 0..15, rows rt*4..rt*4+3
    int h = ct >> 3;
    float acc[4][4], den[4];
#pragma unroll
    for (int r = 0; r < 4; r++) { den[r] = 0.f;
#pragma unroll
        for (int j = 0; j < 4; j++) acc[r][j] = 0.f; }
#pragma unroll 4
    for (int k = 0; k < 32; k++) {
        float4 wv = *(const float4*)&W1[k * DCH + 4 * ct];
#pragma unroll
        for (int r = 0; r < 4; r++) {
            int row = rt * 4 + r;
            float g = (float)hist[row][k] * El[xdl[row] * 132 + h * 33 + k];
            den[r] += g;
            acc[r][0] = fmaf(g, wv.x, acc[r][0]);
            acc[r][1] = fmaf(g, wv.y, acc[r][1]);
            acc[r][2] = fmaf(g, wv.z, acc[r][2]);
            acc[r][3] = fmaf(g, wv.w, acc[r][3]);
        }
    }
    float4 bb = *(const float4*)&b1[4 * ct];
    float bbv[4] = {bb.x, bb.y, bb.z, bb.w};
#pragma unroll
    for (int r = 0; r < 4; r++) {
        float inv = 1.0f / den[r];
#pragma unroll
        for (int j = 0; j < 4; j++) {
            float v = acc[r][j] * inv + bbv[j];
            acc[r][j] = v > 0.f ? v : 0.f;      // acc now holds relu'd h1 values
        }
        int row = r0 + rt * 4 + r;
        if (row < N) {
            union { __half hh[4]; uint2 u; } pk;
#pragma unroll
            for (int j = 0; j < 4; j++) pk.hh[j] = __float2half(acc[r][j]);
            *(uint2*)&h1[(size_t)row * DCH + 4 * ct] = pk.u;
        }
    }
    // ---- fused conv3 logits: 8 FMAs/row + 3-step shfl reduce over 8 head-lanes
    float4 ws = *(const float4*)&was3[h * DCH + 4 * ct];
    float4 wd = *(const float4*)&wad3[h * DCH + 4 * ct];
#pragma unroll
    for (int r = 0; r < 4; r++) {
        float ps = acc[r][0] * ws.x + acc[r][1] * ws.y + acc[r][2] * ws.z + acc[r][3] * ws.w;
        float pd = acc[r][0] * wd.x + acc[r][1] * wd.y + acc[r][2] * wd.z + acc[r][3] * wd.w;
        ps += __shfl_xor(ps, 1);  pd += __shfl_xor(pd, 1);
        ps += __shfl_xor(ps, 2);  pd += __shfl_xor(pd, 2);
        ps += __shfl_xor(ps, 4);  pd += __shfl_xor(pd, 4);
        int row = r0 + rt * 4 + r;
        if ((ct & 7) == 0 && row < N) {
            asrc[row * HEADS + h] = ps;
            adst[row * HEADS + h] = pd;
        }
    }
}

// ================= conv3 gather, head-split: pass hd2 covers channels hd2*64..+63 ======
// wave = 4 edge-groups x 16 lanes; lane16 covers 4 channels (uint2); 2-edge unroll.
// Working set per pass = 12.8 MB (half of h1) -> better per-XCD L2 hit rate.
__global__ __launch_bounds__(256) void k_gather3h(
        const int* __restrict__ rowstart, const int* __restrict__ csr,
        const __half* __restrict__ hp, const float* __restrict__ asrc,
        const float* __restrict__ adst, __half* __restrict__ z, int N, int hd2) {
    int t = threadIdx.x;
    int wid = t >> 6, lane = t & 63;
    int d = blockIdx.x * 4 + wid;
    if (d >= N) return;                        // wave-uniform exit
    int lane16 = lane & 15, grp = lane >> 4;
    int myh = hd2 * 2 + (lane16 >> 3);         // head of my 4 channels
    int cb = hd2 * 64 + lane16 * 4;            // channel base
    float adst_h = adst[d * HEADS + myh];
    int p0 = rowstart[d], p1 = rowstart[d + 1];
    float a[4], b[4];
#pragma unroll
    for (int j = 0; j < 4; j++) { a[j] = 0.f; b[j] = 0.f; }
    float dena = 0.f, denb = 0.f;
    int p = p0 + grp;
    for (; p + 4 < p1; p += 8) {               // 2 edges (p, p+4) in flight per group
        int s0 = csr[p] >> 5;
        int s1 = csr[p + 4] >> 5;
        float ev0 = asrc[s0 * HEADS + myh] + adst_h;
        float ev1 = asrc[s1 * HEADS + myh] + adst_h;
        ev0 = ev0 >= 0.f ? ev0 : NSLOPE * ev0;
        ev1 = ev1 >= 0.f ? ev1 : NSLOPE * ev1;
        float ex0 = __expf(ev0);
        float ex1 = __expf(ev1);
        dena += ex0; denb += ex1;
        const uint2 r0v = *(const uint2*)(hp + (size_t)s0 * DCH + cb);
        const uint2 r1v = *(const uint2*)(hp + (size_t)s1 * DCH + cb);
        const __half2* q0 = (const __half2*)&r0v;
        const __half2* q1 = (const __half2*)&r1v;
#pragma unroll
        for (int j = 0; j < 2; j++) {
            float2 f0 = __half22float2(q0[j]);
            float2 f1 = __half22float2(q1[j]);
            a[2 * j]     = fmaf(ex0, f0.x, a[2 * j]);
            a[2 * j + 1] = fmaf(ex0, f0.y, a[2 * j + 1]);
            b[2 * j]     = fmaf(ex1, f1.x, b[2 * j]);
            b[2 * j + 1] = fmaf(ex1, f1.y, b[2 * j + 1]);
        }
    }
    if (p < p1) {                              // tail edge for this group
        int s0 = csr[p] >> 5;
        float ev0 = asrc[s0 * HEADS + myh] + adst_h;
        ev0 = ev0 >= 0.f ? ev0 : NSLOPE * ev0;
        float ex0 = __expf(ev0);
        dena += ex0;
        const uint2 r0v = *(const uint2*)(hp + (size_t)s0 * DCH + cb);
        const __half2* q0 = (const __half2*)&r0v;
#pragma unroll
        for (int j = 0; j < 2; j++) {
            float2 f0 = __half22float2(q0[j]);
            a[2 * j]     = fmaf(ex0, f0.x, a[2 * j]);
            a[2 * j + 1] = fmaf(ex0, f0.y, a[2 * j + 1]);
        }
    }
    float den = dena + denb;
#pragma unroll
    for (int j = 0; j < 4; j++) a[j] += b[j];
#pragma unroll
    for (int j = 0; j < 4; j++) {
        a[j] += __shfl_xor(a[j], 16);
        a[j] += __shfl_xor(a[j], 32);
    }
    den += __shfl_xor(den, 16);
    den += __shfl_xor(den, 32);
    if (grp == 0) {
        float inv = 1.0f / den;
        union { __half2 h2[2]; uint2 u; } pk;
        pk.h2[0] = __floats2half2_rn(a[0] * inv, a[1] * inv);
        pk.h2[1] = __floats2half2_rn(a[2] * inv, a[3] * inv);
        *(uint2*)(z + (size_t)d * DCH + cb) = pk.u;
    }
}

// ---- parallel mean-pool over fp16 z: 64 threads, half2 channel pairs
__global__ __launch_bounds__(64) void k_pool_partial(
        const __half* __restrict__ h, const int* __restrict__ batch,
        float* __restrict__ pool, int N, int R) {
    int c2 = threadIdx.x;                     // channel pair
    int n0 = blockIdx.x * R;
    if (n0 >= N) return;
    int n1 = n0 + R; if (n1 > N) n1 = N;
    float ax = 0.f, ay = 0.f;
    int curg = batch[n0];
    for (int n = n0; n < n1; n++) {
        int g = batch[n];
        if (g != curg) {
            atomicAdd(&pool[(size_t)curg * DCH + 2 * c2], ax);
            atomicAdd(&pool[(size_t)curg * DCH + 2 * c2 + 1], ay);
            ax = 0.f; ay = 0.f; curg = g;
        }
        __half2 hv = *(const __half2*)(h + (size_t)n * DCH + 2 * c2);
        float2 f = __half22float2(hv);
        ax += f.x; ay += f.y;
    }
    atomicAdd(&pool[(size_t)curg * DCH + 2 * c2], ax);
    atomicAdd(&pool[(size_t)curg * DCH + 2 * c2 + 1], ay);
}

// ---- pooled @ W3 + b3, then @ lin_w + lin_b
__global__ __launch_bounds__(128) void k_final2(
        const float* __restrict__ pool, const int* __restrict__ gstart,
        const float* __restrict__ W3, const float* __restrict__ b3,
        const float* __restrict__ lw, const float* __restrict__ lb,
        float* __restrict__ out, int G) {
    __shared__ float pooled[DCH];
    __shared__ float t3[DCH];
    int g = blockIdx.x, c = threadIdx.x;
    float cnt = (float)(gstart[g + 1] - gstart[g]);
    pooled[c] = pool[(size_t)g * DCH + c] / fmaxf(cnt, 1.f);
    __syncthreads();
    float acc = b3[c];
#pragma unroll 8
    for (int k = 0; k < DCH; k++) acc = fmaf(pooled[k], W3[k * DCH + c], acc);
    t3[c] = acc;
    __syncthreads();
    if (c < OUTC) {
        float o = lb[c];
#pragma unroll 8
        for (int k = 0; k < DCH; k++) o = fmaf(t3[k], lw[k * OUTC + c], o);
        out[g * OUTC + c] = o;
    }
}

extern "C" void kernel_launch(void* const* d_in, const int* in_sizes, int n_in,
                              void* d_out, int out_size, void* d_ws, size_t ws_size,
                              hipStream_t stream) {
    const int*   x    = (const int*)d_in[0];
    const int*   eidx = (const int*)d_in[1];
    const int*   batch= (const int*)d_in[2];
    const float* W1   = (const float*)d_in[3];
    const float* as1  = (const float*)d_in[4];
    const float* ad1  = (const float*)d_in[5];
    const float* b1   = (const float*)d_in[6];
    const float* W3   = (const float*)d_in[7];
    const float* as3  = (const float*)d_in[8];
    const float* ad3  = (const float*)d_in[9];
    const float* b3   = (const float*)d_in[10];
    const float* lw   = (const float*)d_in[11];
    const float* lb   = (const float*)d_in[12];
    float* out = (float*)d_out;

    const int N  = in_sizes[0];
    const int E  = in_sizes[1] / 2;
    const int G  = out_size / OUTC;
    const int EP = E + N;
    const int* esrc = eidx;
    const int* edst = eidx + E;

    // ---- workspace layout ----
    float*  zslot   = (float*)d_ws;                       // [N,128] region; fp16 z lives here
    __half* h1      = (__half*)(zslot + (size_t)N * DCH); // [N,128] fp16
    float*  asrc3   = (float*)(h1 + (size_t)N * DCH);     // [N,4]
    float*  adst3   = asrc3 + (size_t)N * HEADS;          // [N,4]
    int*    deg     = (int*)(adst3 + (size_t)N * HEADS);  // [N]
    int*    rowstart= deg + N;                            // [N+1]
    int*    bsum    = rowstart + (N + 1);                 // [<=1024]
    int*    csr     = bsum + 1024;                        // [EP] packed (s<<5)|cls
    unsigned short* rank = (unsigned short*)(csr + EP);   // [EP] packed (r<<5)|cls
    int*    gstart  = (int*)(rank + EP);                  // [G+1]
    float*  pool    = (float*)(gstart + (G + 1));         // [G,128]
    float*  EXPT2   = pool + (size_t)G * DCH;             // [32,128]
    float*  was3    = EXPT2 + 32 * DCH;                   // [4,128]
    float*  wad3    = was3 + HEADS * DCH;                 // [4,128]
    __half* z       = (__half*)zslot;                     // [N,128] fp16

    const int BS = 256;
    const int nb = (N + SCAN_ELEMS - 1) / SCAN_ELEMS;

    // ---- CSR build (atomic-free scatter via packed rank) ----
    hipMemsetAsync(deg, 0, (size_t)N * sizeof(int), stream);
    k_deg<<<(EP + BS - 1) / BS, BS, 0, stream>>>(esrc, edst, x, E, N, deg, rank);
    k_scan_a<<<nb, SCAN_T, 0, stream>>>(deg, rowstart, bsum, N);
    k_scanb_tables<<<2, 1024, 0, stream>>>(bsum, nb, W1, as1, ad1, W3, as3, ad3,
                                           EXPT2, was3, wad3);
    k_scan_c_bounds<<<(N + 1 + BS - 1) / BS, BS, 0, stream>>>(rowstart, bsum, batch,
                                                              gstart, pool, N, G);
    k_scatter1p<<<(EP + BS - 1) / BS, BS, 0, stream>>>(esrc, edst, E, N, rowstart, rank, csr);

    // ---- conv1 (block GEMM + fused conv3 logits), 64 nodes/block ----
    k_conv1b<<<(N + BN1 - 1) / BN1, 512, 0, stream>>>(rowstart, csr, x, W1, EXPT2, b1,
                                                      was3, wad3, h1, asrc3, adst3, N);

    // ---- conv3 gather on h1: two serialized head-pair passes for L2 locality ----
    k_gather3h<<<(N + 3) / 4, 256, 0, stream>>>(rowstart, csr, h1, asrc3, adst3, z, N, 0);
    k_gather3h<<<(N + 3) / 4, 256, 0, stream>>>(rowstart, csr, h1, asrc3, adst3, z, N, 1);

    // ---- pool + (W3,b3) + classifier ----
    {
        int R = (N + POOL_BLOCKS - 1) / POOL_BLOCKS;
        k_pool_partial<<<POOL_BLOCKS, 64, 0, stream>>>(z, batch, pool, N, R);
    }
    k_final2<<<G, 128, 0, stream>>>(pool, gstart, W3, b3, lw, lb, out, G);
}

// Round 21
// 178.106 us; speedup vs baseline: 1.1477x; 1.1477x over previous
//
#include <hip/hip_runtime.h>
#include <hip/hip_fp16.h>

#define HEADS 4
#define HID 32
#define DCH 128            // HEADS*HID
#define OUTC 10
#define NSLOPE 0.2f

#define SCAN_T 256
#define SCAN_PT 8
#define SCAN_ELEMS (SCAN_T * SCAN_PT)   // 2048 per scan block

#define POOL_BLOCKS 2048
#define BN1 64             // nodes per conv1 block (512 threads)
#define SC_TILES 256       // scatter: tiles per dst-range (grid = 8*SC_TILES)

// ================= CSR build (dst-major) =================
// deg pass records rank AND class packed in 16 bits -> scatter is atomic-free
// and needs no random x gather.
__global__ void k_deg(const int* __restrict__ esrc, const int* __restrict__ edst,
                      const int* __restrict__ x, int E, int N,
                      int* __restrict__ deg, unsigned short* __restrict__ rank) {
    int e = blockIdx.x * blockDim.x + threadIdx.x;
    int EP = E + N;
    if (e >= EP) return;
    int s, d;
    if (e < E) { s = esrc[e]; d = edst[e]; } else { s = e - E; d = s; }
    int r = atomicAdd(&deg[d], 1);
    rank[e] = (unsigned short)((r << 5) | x[s]);
}

__global__ void k_scan_a(const int* __restrict__ deg, int* __restrict__ rowstart,
                         int* __restrict__ bsum, int N) {
    __shared__ int sh[SCAN_T];
    int base = blockIdx.x * SCAN_ELEMS;
    int t = threadIdx.x;
    int v[SCAN_PT];
    int s = 0;
#pragma unroll
    for (int i = 0; i < SCAN_PT; i++) {
        int idx = base + t * SCAN_PT + i;
        int dv = (idx < N) ? deg[idx] : 0;
        s += dv; v[i] = s;
    }
    sh[t] = s;
    __syncthreads();
    for (int off = 1; off < SCAN_T; off <<= 1) {
        int add = (t >= off) ? sh[t - off] : 0;
        __syncthreads();
        sh[t] += add;
        __syncthreads();
    }
    int excl = (t > 0) ? sh[t - 1] : 0;
#pragma unroll
    for (int i = 0; i < SCAN_PT; i++) {
        int idx = base + t * SCAN_PT + i;
        if (idx < N) rowstart[idx + 1] = v[i] + excl;
    }
    if (t == SCAN_T - 1) bsum[blockIdx.x] = sh[t];
}

// ---- block 0: exclusive scan of bsum; block 1: build EXPT2/was3/wad3 tables
__global__ void k_scanb_tables(int* __restrict__ bsum, int nb,
        const float* __restrict__ W1, const float* __restrict__ as1, const float* __restrict__ ad1,
        const float* __restrict__ W3, const float* __restrict__ as3, const float* __restrict__ ad3,
        float* __restrict__ EXPT2, float* __restrict__ was3, float* __restrict__ wad3) {
    if (blockIdx.x == 0) {
        __shared__ int sh[1024];
        int t = threadIdx.x;
        sh[t] = (t < nb) ? bsum[t] : 0;
        __syncthreads();
        for (int off = 1; off < 1024; off <<= 1) {
            int add = (t >= off) ? sh[t - off] : 0;
            __syncthreads();
            sh[t] += add;
            __syncthreads();
        }
        if (t < nb) bsum[t] = (t > 0) ? sh[t - 1] : 0;
    } else {
        __shared__ float ts[32][HEADS], td[32][HEADS];
        int t = threadIdx.x;
        if (t < 128) {
            int cs = t >> 2, h = t & 3;
            const float* w = W1 + cs * DCH + h * HID;
            const float* a = as1 + h * HID;
            const float* b = ad1 + h * HID;
            float s1 = 0.f, s2 = 0.f;
#pragma unroll
            for (int j = 0; j < HID; j++) { float wv = w[j]; s1 = fmaf(wv, a[j], s1); s2 = fmaf(wv, b[j], s2); }
            ts[cs][h] = s1; td[cs][h] = s2;
        }
        __syncthreads();
        if (t < 128) {
            int h = t >> 5, cs = t & 31;
            for (int cd = 0; cd < 32; cd++) {
                float ev = ts[cs][h] + td[cd][h];
                ev = ev >= 0.f ? ev : NSLOPE * ev;
                EXPT2[cd * DCH + t] = __expf(ev);
            }
            for (int hh = 0; hh < HEADS; hh++) {
                const float* wr = W3 + (size_t)t * DCH + hh * HID;
                const float* a = as3 + hh * HID;
                const float* b = ad3 + hh * HID;
                float s1 = 0.f, s2 = 0.f;
#pragma unroll
                for (int j = 0; j < HID; j++) { float wv = wr[j]; s1 = fmaf(wv, a[j], s1); s2 = fmaf(wv, b[j], s2); }
                was3[hh * DCH + t] = s1; wad3[hh * DCH + t] = s2;
            }
        }
    }
}

// ---- scan finish + graph bounds + pool zero (merged elementwise pass)
__global__ void k_scan_c_bounds(int* __restrict__ rowstart, const int* __restrict__ boff,
                                const int* __restrict__ batch, int* __restrict__ gstart,
                                float* __restrict__ pool, int N, int G) {
    int i = blockIdx.x * blockDim.x + threadIdx.x;
    if (i < G * DCH) pool[i] = 0.f;
    if (i < N) {
        rowstart[i + 1] += boff[i / SCAN_ELEMS];
        if (i == 0) rowstart[0] = 0;
    }
    if (i > N) return;
    if (i == 0) {
        int b0 = batch[0];
        for (int g = 0; g <= b0; g++) gstart[g] = 0;
    } else if (i == N) {
        int bl = batch[N - 1];
        for (int g = bl + 1; g <= G; g++) gstart[g] = N;
    } else {
        int b = batch[i], bp = batch[i - 1];
        for (int g = bp + 1; g <= b; g++) gstart[g] = i;
    }
}

// ---- XCD-range-partitioned scatter, atomic-free via packed rank16.
__global__ void k_scatter3(const int* __restrict__ esrc, const int* __restrict__ edst,
                           int E, int N, const int* __restrict__ rowstart,
                           const unsigned short* __restrict__ rank,
                           int* __restrict__ csr) {
    int rng  = blockIdx.x & 7;
    int tile = blockIdx.x >> 3;
    int ntiles = gridDim.x >> 3;
    int lo = rng * (N >> 3);
    int hi = (rng == 7) ? N : lo + (N >> 3);
    int EP = E + N;
    int stride = ntiles * blockDim.x;
    for (int e = tile * blockDim.x + threadIdx.x; e < EP; e += stride) {
        int s, d;
        if (e < E) { s = esrc[e]; d = edst[e]; } else { s = e - E; d = s; }
        if (d < lo || d >= hi) continue;
        unsigned short rk = rank[e];
        int pos = rowstart[d] + (rk >> 5);
        csr[pos] = (s << 5) | (rk & 31);
    }
}

// ================= conv1: padded-LDS histogram + GEMM + fused conv3 logits ========
// 64 nodes per block, 512 threads; per-thread shape same as before.
__global__ __launch_bounds__(512) void k_conv1b(
        const int* __restrict__ rowstart, const int* __restrict__ csr,
        const int* __restrict__ x, const float* __restrict__ W1,
        const float* __restrict__ EXPT2, const float* __restrict__ b1,
        const float* __restrict__ was3, const float* __restrict__ wad3,
        __half* __restrict__ h1, float* __restrict__ asrc, float* __restrict__ adst,
        int N) {
    __shared__ float El[32 * 132 + 1];      // EXPT2 padded [cd*132 + h*33 + k]
    __shared__ int   hist[BN1][33];
    __shared__ int   xdl[BN1];
    int t = threadIdx.x;
    int r0 = blockIdx.x * BN1;
    for (int i = t; i < 32 * DCH; i += 512) {
        int cd = i >> 7, rem = i & 127;
        int hh = rem >> 5, kk = rem & 31;
        El[cd * 132 + hh * 33 + kk] = EXPT2[i];
    }
    for (int i = t; i < BN1 * 33; i += 512) ((int*)hist)[i] = 0;
    if (t < BN1) {
        int node = r0 + t;
        xdl[t] = (node < N) ? x[node] : 0;
    }
    __syncthreads();
    {   // 8 threads per node build its class histogram (streaming csr reads)
        int ln = t >> 3, sub = t & 7;
        int node = r0 + ln;
        if (node < N) {
            int p0 = rowstart[node], p1 = rowstart[node + 1];
            for (int p = p0 + sub; p < p1; p += 8)
                atomicAdd(&hist[ln][csr[p] & 31], 1);
        }
    }
    __syncthreads();
    int ct = t & 31, rt = t >> 5;           // rt 0..15, rows rt*4..rt*4+3
    int h = ct >> 3;
    float acc[4][4], den[4];
#pragma unroll
    for (int r = 0; r < 4; r++) { den[r] = 0.f;
#pragma unroll
        for (int j = 0; j < 4; j++) acc[r][j] = 0.f; }
#pragma unroll 4
    for (int k = 0; k < 32; k++) {
        float4 wv = *(const float4*)&W1[k * DCH + 4 * ct];
#pragma unroll
        for (int r = 0; r < 4; r++) {
            int row = rt * 4 + r;
            float g = (float)hist[row][k] * El[xdl[row] * 132 + h * 33 + k];
            den[r] += g;
            acc[r][0] = fmaf(g, wv.x, acc[r][0]);
            acc[r][1] = fmaf(g, wv.y, acc[r][1]);
            acc[r][2] = fmaf(g, wv.z, acc[r][2]);
            acc[r][3] = fmaf(g, wv.w, acc[r][3]);
        }
    }
    float4 bb = *(const float4*)&b1[4 * ct];
    float bbv[4] = {bb.x, bb.y, bb.z, bb.w};
#pragma unroll
    for (int r = 0; r < 4; r++) {
        float inv = 1.0f / den[r];
#pragma unroll
        for (int j = 0; j < 4; j++) {
            float v = acc[r][j] * inv + bbv[j];
            acc[r][j] = v > 0.f ? v : 0.f;      // acc now holds relu'd h1 values
        }
        int row = r0 + rt * 4 + r;
        if (row < N) {
            union { __half hh[4]; uint2 u; } pk;
#pragma unroll
            for (int j = 0; j < 4; j++) pk.hh[j] = __float2half(acc[r][j]);
            *(uint2*)&h1[(size_t)row * DCH + 4 * ct] = pk.u;
        }
    }
    // ---- fused conv3 logits: 8 FMAs/row + 3-step shfl reduce over 8 head-lanes
    float4 ws = *(const float4*)&was3[h * DCH + 4 * ct];
    float4 wd = *(const float4*)&wad3[h * DCH + 4 * ct];
#pragma unroll
    for (int r = 0; r < 4; r++) {
        float ps = acc[r][0] * ws.x + acc[r][1] * ws.y + acc[r][2] * ws.z + acc[r][3] * ws.w;
        float pd = acc[r][0] * wd.x + acc[r][1] * wd.y + acc[r][2] * wd.z + acc[r][3] * wd.w;
        ps += __shfl_xor(ps, 1);  pd += __shfl_xor(pd, 1);
        ps += __shfl_xor(ps, 2);  pd += __shfl_xor(pd, 2);
        ps += __shfl_xor(ps, 4);  pd += __shfl_xor(pd, 4);
        int row = r0 + rt * 4 + r;
        if ((ct & 7) == 0 && row < N) {
            asrc[row * HEADS + h] = ps;
            adst[row * HEADS + h] = pd;
        }
    }
}

// ================= conv3 gather: wave-per-node, 16 lanes/row, 2-edge unroll ============
__global__ __launch_bounds__(256) void k_gather3w(
        const int* __restrict__ rowstart, const int* __restrict__ csr,
        const __half* __restrict__ hp, const float* __restrict__ asrc,
        const float* __restrict__ adst, __half* __restrict__ z, int N) {
    int t = threadIdx.x;
    int wid = t >> 6, lane = t & 63;
    int d = blockIdx.x * 4 + wid;
    if (d >= N) return;                        // wave-uniform exit
    int lane16 = lane & 15, grp = lane >> 4;
    int myh = lane16 >> 2;                     // head of my 8 channels
    float adst_h = adst[d * HEADS + myh];
    int p0 = rowstart[d], p1 = rowstart[d + 1];
    float a[8], b[8];
#pragma unroll
    for (int j = 0; j < 8; j++) { a[j] = 0.f; b[j] = 0.f; }
    float dena = 0.f, denb = 0.f;
    int p = p0 + grp;
    for (; p + 4 < p1; p += 8) {               // 2 edges (p, p+4) in flight per group
        int s0 = csr[p] >> 5;
        int s1 = csr[p + 4] >> 5;
        float ev0 = asrc[s0 * HEADS + myh] + adst_h;
        float ev1 = asrc[s1 * HEADS + myh] + adst_h;
        ev0 = ev0 >= 0.f ? ev0 : NSLOPE * ev0;
        ev1 = ev1 >= 0.f ? ev1 : NSLOPE * ev1;
        float ex0 = __expf(ev0);
        float ex1 = __expf(ev1);
        dena += ex0; denb += ex1;
        const uint4 r0v = *(const uint4*)(hp + (size_t)s0 * DCH + lane16 * 8);
        const uint4 r1v = *(const uint4*)(hp + (size_t)s1 * DCH + lane16 * 8);
        const __half2* q0 = (const __half2*)&r0v;
        const __half2* q1 = (const __half2*)&r1v;
#pragma unroll
        for (int j = 0; j < 4; j++) {
            float2 f0 = __half22float2(q0[j]);
            float2 f1 = __half22float2(q1[j]);
            a[2 * j]     = fmaf(ex0, f0.x, a[2 * j]);
            a[2 * j + 1] = fmaf(ex0, f0.y, a[2 * j + 1]);
            b[2 * j]     = fmaf(ex1, f1.x, b[2 * j]);
            b[2 * j + 1] = fmaf(ex1, f1.y, b[2 * j + 1]);
        }
    }
    if (p < p1) {                              // tail edge for this group
        int s0 = csr[p] >> 5;
        float ev0 = asrc[s0 * HEADS + myh] + adst_h;
        ev0 = ev0 >= 0.f ? ev0 : NSLOPE * ev0;
        float ex0 = __expf(ev0);
        dena += ex0;
        const uint4 r0v = *(const uint4*)(hp + (size_t)s0 * DCH + lane16 * 8);
        const __half2* q0 = (const __half2*)&r0v;
#pragma unroll
        for (int j = 0; j < 4; j++) {
            float2 f0 = __half22float2(q0[j]);
            a[2 * j]     = fmaf(ex0, f0.x, a[2 * j]);
            a[2 * j + 1] = fmaf(ex0, f0.y, a[2 * j + 1]);
        }
    }
    float den = dena + denb;
#pragma unroll
    for (int j = 0; j < 8; j++) a[j] += b[j];
#pragma unroll
    for (int j = 0; j < 8; j++) {
        a[j] += __shfl_xor(a[j], 16);
        a[j] += __shfl_xor(a[j], 32);
    }
    den += __shfl_xor(den, 16);
    den += __shfl_xor(den, 32);
    if (grp == 0) {
        float inv = 1.0f / den;
        union { __half2 h2[4]; uint4 u; } pk;
#pragma unroll
        for (int j = 0; j < 4; j++)
            pk.h2[j] = __floats2half2_rn(a[2 * j] * inv, a[2 * j + 1] * inv);
        *(uint4*)(z + (size_t)d * DCH + lane16 * 8) = pk.u;
    }
}

// ---- parallel mean-pool over fp16 z: 64 threads, half2 channel pairs
__global__ __launch_bounds__(64) void k_pool_partial(
        const __half* __restrict__ h, const int* __restrict__ batch,
        float* __restrict__ pool, int N, int R) {
    int c2 = threadIdx.x;                     // channel pair
    int n0 = blockIdx.x * R;
    if (n0 >= N) return;
    int n1 = n0 + R; if (n1 > N) n1 = N;
    float ax = 0.f, ay = 0.f;
    int curg = batch[n0];
    for (int n = n0; n < n1; n++) {
        int g = batch[n];
        if (g != curg) {
            atomicAdd(&pool[(size_t)curg * DCH + 2 * c2], ax);
            atomicAdd(&pool[(size_t)curg * DCH + 2 * c2 + 1], ay);
            ax = 0.f; ay = 0.f; curg = g;
        }
        __half2 hv = *(const __half2*)(h + (size_t)n * DCH + 2 * c2);
        float2 f = __half22float2(hv);
        ax += f.x; ay += f.y;
    }
    atomicAdd(&pool[(size_t)curg * DCH + 2 * c2], ax);
    atomicAdd(&pool[(size_t)curg * DCH + 2 * c2 + 1], ay);
}

// ---- pooled @ W3 + b3, then @ lin_w + lin_b
__global__ __launch_bounds__(128) void k_final2(
        const float* __restrict__ pool, const int* __restrict__ gstart,
        const float* __restrict__ W3, const float* __restrict__ b3,
        const float* __restrict__ lw, const float* __restrict__ lb,
        float* __restrict__ out, int G) {
    __shared__ float pooled[DCH];
    __shared__ float t3[DCH];
    int g = blockIdx.x, c = threadIdx.x;
    float cnt = (float)(gstart[g + 1] - gstart[g]);
    pooled[c] = pool[(size_t)g * DCH + c] / fmaxf(cnt, 1.f);
    __syncthreads();
    float acc = b3[c];
#pragma unroll 8
    for (int k = 0; k < DCH; k++) acc = fmaf(pooled[k], W3[k * DCH + c], acc);
    t3[c] = acc;
    __syncthreads();
    if (c < OUTC) {
        float o = lb[c];
#pragma unroll 8
        for (int k = 0; k < DCH; k++) o = fmaf(t3[k], lw[k * OUTC + c], o);
        out[g * OUTC + c] = o;
    }
}

extern "C" void kernel_launch(void* const* d_in, const int* in_sizes, int n_in,
                              void* d_out, int out_size, void* d_ws, size_t ws_size,
                              hipStream_t stream) {
    const int*   x    = (const int*)d_in[0];
    const int*   eidx = (const int*)d_in[1];
    const int*   batch= (const int*)d_in[2];
    const float* W1   = (const float*)d_in[3];
    const float* as1  = (const float*)d_in[4];
    const float* ad1  = (const float*)d_in[5];
    const float* b1   = (const float*)d_in[6];
    const float* W3   = (const float*)d_in[7];
    const float* as3  = (const float*)d_in[8];
    const float* ad3  = (const float*)d_in[9];
    const float* b3   = (const float*)d_in[10];
    const float* lw   = (const float*)d_in[11];
    const float* lb   = (const float*)d_in[12];
    float* out = (float*)d_out;

    const int N  = in_sizes[0];
    const int E  = in_sizes[1] / 2;
    const int G  = out_size / OUTC;
    const int EP = E + N;
    const int* esrc = eidx;
    const int* edst = eidx + E;

    // ---- workspace layout ----
    float*  zslot   = (float*)d_ws;                       // [N,128] region; fp16 z lives here
    __half* h1      = (__half*)(zslot + (size_t)N * DCH); // [N,128] fp16
    float*  asrc3   = (float*)(h1 + (size_t)N * DCH);     // [N,4]
    float*  adst3   = asrc3 + (size_t)N * HEADS;          // [N,4]
    int*    deg     = (int*)(adst3 + (size_t)N * HEADS);  // [N]
    int*    rowstart= deg + N;                            // [N+1]
    int*    bsum    = rowstart + (N + 1);                 // [<=1024]
    int*    csr     = bsum + 1024;                        // [EP] packed (s<<5)|cls
    unsigned short* rank = (unsigned short*)(csr + EP);   // [EP] packed (r<<5)|cls
    int*    gstart  = (int*)(rank + EP);                  // [G+1]
    float*  pool    = (float*)(gstart + (G + 1));         // [G,128]
    float*  EXPT2   = pool + (size_t)G * DCH;             // [32,128]
    float*  was3    = EXPT2 + 32 * DCH;                   // [4,128]
    float*  wad3    = was3 + HEADS * DCH;                 // [4,128]
    __half* z       = (__half*)zslot;                     // [N,128] fp16

    const int BS = 256;
    const int nb = (N + SCAN_ELEMS - 1) / SCAN_ELEMS;

    // ---- CSR build (atomic-free scatter via packed rank) ----
    hipMemsetAsync(deg, 0, (size_t)N * sizeof(int), stream);
    k_deg<<<(EP + BS - 1) / BS, BS, 0, stream>>>(esrc, edst, x, E, N, deg, rank);
    k_scan_a<<<nb, SCAN_T, 0, stream>>>(deg, rowstart, bsum, N);
    k_scanb_tables<<<2, 1024, 0, stream>>>(bsum, nb, W1, as1, ad1, W3, as3, ad3,
                                           EXPT2, was3, wad3);
    k_scan_c_bounds<<<(N + 1 + BS - 1) / BS, BS, 0, stream>>>(rowstart, bsum, batch,
                                                              gstart, pool, N, G);
    k_scatter3<<<8 * SC_TILES, BS, 0, stream>>>(esrc, edst, E, N, rowstart, rank, csr);

    // ---- conv1 (block GEMM + fused conv3 logits), 64 nodes/block ----
    k_conv1b<<<(N + BN1 - 1) / BN1, 512, 0, stream>>>(rowstart, csr, x, W1, EXPT2, b1,
                                                      was3, wad3, h1, asrc3, adst3, N);

    // ---- conv3 gather on h1 ----
    k_gather3w<<<(N + 3) / 4, 256, 0, stream>>>(rowstart, csr, h1, asrc3, adst3, z, N);

    // ---- pool + (W3,b3) + classifier ----
    {
        int R = (N + POOL_BLOCKS - 1) / POOL_BLOCKS;
        k_pool_partial<<<POOL_BLOCKS, 64, 0, stream>>>(z, batch, pool, N, R);
    }
    k_final2<<<G, 128, 0, stream>>>(pool, gstart, W3, b3, lw, lb, out, G);
}